// Round 16
// baseline (94.924 us; speedup 1.0000x reference)
//
#include <hip/hip_runtime.h>
#include <hip/hip_bf16.h>

// ---------------------------------------------------------------------------
// Round 16 = R14 (best tail config) + tail-x LDS staging: x0 rows 0..31 of
// each tree staged coalesced into padded bf16 LDS images [32][40] at kernel
// start (loads overlap weight staging, one barrier). l4/l3..l0 x reads become
// aligned ds_read_b128 (~120cy) instead of scattered L3 loads (~600cy).
// +10.2 KB LDS (73.2 KB total, still 2 blocks/CU), +9 short-lived VGPRs.
// ---------------------------------------------------------------------------

typedef __attribute__((ext_vector_type(8))) short s8v;   // 8 bf16
typedef __attribute__((ext_vector_type(4))) float f4v;   // MFMA C/D
typedef unsigned short u16;
typedef unsigned int   u32;

__device__ __forceinline__ u16 f2bf(float f) {
    return __builtin_bit_cast(u16, __float2bfloat16(f));
}
__device__ __forceinline__ f4v mfma16(s8v a, s8v b, f4v c) {
    return __builtin_amdgcn_mfma_f32_16x16x32_bf16(a, b, c, 0, 0, 0);
}
#define SWZ(r) ((((r) & 1) | (((r) >> 1) & 6)) << 3)

__device__ __forceinline__ u32 pk2(float a, float b) {
    return (u32)f2bf(fmaxf(a, 0.f)) | ((u32)f2bf(fmaxf(b, 0.f)) << 16);
}
__device__ __forceinline__ s8v pkfrag(f4v h0, f4v h1) {
    int4 d;
    d.x = (int)pk2(h0[0], h0[1]); d.y = (int)pk2(h0[2], h0[3]);
    d.z = (int)pk2(h1[0], h1[1]); d.w = (int)pk2(h1[2], h1[3]);
    return __builtin_bit_cast(s8v, d);
}
__device__ __forceinline__ s8v mkB0(float4 A, float4 B) {
    s8v r;
    r[0]=(short)f2bf(A.x); r[1]=(short)f2bf(A.y); r[2]=(short)f2bf(A.z); r[3]=(short)f2bf(A.w);
    r[4]=(short)f2bf(B.x); r[5]=(short)f2bf(B.y); r[6]=(short)f2bf(B.z); r[7]=(short)f2bf(B.w);
    return r;
}
__device__ __forceinline__ s8v mkB1(float4 T) {   // T pre-zeroed for lq!=0
    s8v r = (s8v){0,0,0,0,0,0,0,0};
    r[0]=(short)f2bf(T.y); r[1]=(short)f2bf(T.z); r[2]=(short)f2bf(T.w);
    return r;
}
__device__ __forceinline__ s8v xB0(const float* __restrict__ xr, int lq) {
    return mkB0(*(const float4*)(xr + lq * 8), *(const float4*)(xr + lq * 8 + 4));
}
__device__ __forceinline__ s8v xB1(const float* __restrict__ xr, int lq) {
    s8v r = (s8v){0,0,0,0,0,0,0,0};
    if (lq == 0) {
        float4 T = *(const float4*)(xr + 31);   // k31..34
        r[0]=(short)f2bf(T.y); r[1]=(short)f2bf(T.z); r[2]=(short)f2bf(T.w);
    }
    return r;
}
__device__ __forceinline__ s8v wread(const u16* w, int stride, int row, int ks, int lq) {
    return *(const s8v*)(w + row * stride + ks * 32 + lq * 8);
}
__device__ __forceinline__ f4v bias4(const float* __restrict__ b) {
    float4 t = *(const float4*)b; return (f4v){t.x, t.y, t.z, t.w};
}
__device__ __forceinline__ int sigp(int rho, int s, int h) {
    return 32*s + 4*h + ((rho & 12) << 1) + (rho & 3);
}

// ---------------------------------------------------------------------------
__global__ void prep_kernel(const float* __restrict__ W_emb, const float* __restrict__ b_emb,
                            const float* __restrict__ W0, const float* __restrict__ b0,
                            const float* __restrict__ W1, const float* __restrict__ b1,
                            u16* __restrict__ wt1, u16* __restrict__ wt0,
                            float* __restrict__ b1p, float* __restrict__ b0p)
{
    int idx = blockIdx.x * 256 + threadIdx.x;
    if (idx < 64 * 192) {
        int h = idx / 192, k = idx % 192;
        float v;
        if (k < 32) { v = 0.f; for (int e = 0; e < 64; e++) v = fmaf(W1[h*195+e], W_emb[e*32+k], v); }
        else if (k < 35)  v = W1[h*195 + 64 + (k - 32)];
        else if (k < 64)  v = 0.f;
        else              v = W1[h*195 + 67 + (k - 64)];   // hL(64) then hR(64)
        wt1[h*192 + k] = f2bf(v);
    } else if (idx < 64*192 + 64*64) {
        int j = idx - 64*192; int h = j >> 6, k = j & 63;
        float v;
        if (k < 32)      { v = 0.f; for (int e = 0; e < 64; e++) v = fmaf(W0[h*67+e], W_emb[e*32+k], v); }
        else if (k < 35)   v = W0[h*67 + 64 + (k - 32)];
        else               v = 0.f;
        wt0[h*64 + k] = f2bf(v);
    } else if (idx < 64*192 + 64*64 + 64) {
        int h = idx - (64*192 + 64*64);
        float v = b1[h];
        for (int e = 0; e < 64; e++) v = fmaf(W1[h*195+e], b_emb[e], v);
        b1p[h] = v;
    } else if (idx < 64*192 + 64*64 + 128) {
        int h = idx - (64*192 + 64*64 + 64);
        float v = b0[h];
        for (int e = 0; e < 64; e++) v = fmaf(W0[h*67+e], b_emb[e], v);
        b0p[h] = v;
    }
}

// ---------------------------------------------------------------------------
__global__ __launch_bounds__(512, 2) void tree_all(
    const float* __restrict__ x0,
    const u16* __restrict__ wt1g, const u16* __restrict__ wt0g,
    const float* __restrict__ b1p, const float* __restrict__ b0p,
    float* __restrict__ h0out)
{
    __shared__ __align__(16) u16 wt1s[64 * 200];        // 25.6 KB, pad stride 200
    __shared__ __align__(16) u16 wt0s[64 * 40 + 64];    // 5.25 KB + guard
    __shared__ __align__(16) u16 buf6[4 * 64 * 64];     // 32 KB: 4 tree-slices
    __shared__ __align__(16) u16 xts[4 * 32 * 40];      // 10.2 KB: tail x rows 0..31

    const int tid = threadIdx.x;
    const int l   = tid & 63;
    const int w   = tid >> 6;      // 0..7
    const int lq  = l >> 4;
    const int rho = l & 15;
    const int pair = w >> 2;       // tree-pair within block
    const int c    = w & 3;        // chain
    const int tA = blockIdx.x * 4 + 2 * pair;
    const int tB = tA + 1;
    const float* xbA = x0 + (size_t)tA * 511 * 35;
    const float* xbB = x0 + (size_t)tB * 511 * 35;

    // ---- leaf q0 x prefetch: issued before staging, lands under it ----
    const float* xq0A = xbA + (size_t)(255 + 64*c + 4*rho) * 35;
    const float* xq0B = xbB + (size_t)(255 + 64*c + 4*rho) * 35;
    float4 pAa = *(const float4*)(xq0A + lq*8);
    float4 pAb = *(const float4*)(xq0A + lq*8 + 4);
    float4 pAt = (lq == 0) ? *(const float4*)(xq0A + 31) : float4{0.f,0.f,0.f,0.f};
    float4 pBa = *(const float4*)(xq0B + lq*8);
    float4 pBb = *(const float4*)(xq0B + lq*8 + 4);
    float4 pBt = (lq == 0) ? *(const float4*)(xq0B + 31) : float4{0.f,0.f,0.f,0.f};

    // ---- tail-x staging loads (rows 0..31 of the block's 4 trees) ----
    float sx[9];
    const float* xt0 = x0 + (size_t)(blockIdx.x * 4) * 511 * 35;
    #pragma unroll
    for (int t = 0; t < 9; t++) {
        int i = t*512 + tid;                 // 0..4479 (4 trees x 1120 dwords)
        int tr = i / 1120, j = i - tr*1120;
        sx[t] = (i < 4480) ? xt0[(size_t)tr * 511 * 35 + j] : 0.f;
    }

    // ---- stage weights (coalesced dwords) ----
    {
        u32* d1 = (u32*)wt1s; const u32* s1 = (const u32*)wt1g;
        #pragma unroll
        for (int t = 0; t < 12; t++) {
            int i = t*512 + tid;                 // 6144 dwords exactly
            int row = i / 96, kk = i - row*96;
            d1[row*100 + kk] = s1[row*96 + kk];
        }
        u32* d0 = (u32*)wt0s; const u32* s0 = (const u32*)wt0g;
        #pragma unroll
        for (int t = 0; t < 3; t++) {
            int i = t*512 + tid;
            if (i < 1280) { int row = i / 20, kk = i - row*20; d0[row*20 + kk] = s0[row*32 + kk]; }
        }
        if (tid < 32) ((u32*)(wt0s + 64*40))[tid] = 0;   // guard
    }

    // ---- write tail-x image (waits on sx loads only) + zero pads ----
    #pragma unroll
    for (int t = 0; t < 9; t++) {
        int i = t*512 + tid;
        if (i < 4480) {
            int tr = i / 1120, j = i - tr*1120;
            int row = j / 35, col = j - row*35;
            xts[tr*1280 + row*40 + col] = f2bf(sx[t]);
        }
    }
    if (tid < 128) {
        int b = tid * 40;
        for (int cx = 35; cx < 40; cx++) xts[b + cx] = 0;
    }
    __syncthreads();

    // ================= leaf (both trees share WL) =================
    s8v TLA[4][2], TLB[4][2];
    {
        s8v WL[4][2]; f4v bL[4];
        #pragma unroll
        for (int i = 0; i < 4; i++) {
            int sg = sigp(rho, i >> 1, i & 1);
            WL[i][0] = wread(wt0s, 40, sg, 0, lq);
            WL[i][1] = wread(wt0s, 40, sg, 1, lq);
            bL[i] = bias4(b0p + 32*(i>>1) + 8*lq + 4*(i&1));
        }
        auto leafstep = [&](s8v xaA, s8v xtA, s8v xaB, s8v xtB, int q) {
            f4v aA[4], aB[4];
            #pragma unroll
            for (int i = 0; i < 4; i++) { aA[i] = bL[i]; aB[i] = bL[i]; }
            #pragma unroll
            for (int i = 0; i < 4; i++) {
                aA[i] = mfma16(WL[i][0], xaA, aA[i]);
                aA[i] = mfma16(WL[i][1], xtA, aA[i]);
                aB[i] = mfma16(WL[i][0], xaB, aB[i]);
                aB[i] = mfma16(WL[i][1], xtB, aB[i]);
            }
            TLA[q][0] = pkfrag(aA[0], aA[1]); TLA[q][1] = pkfrag(aA[2], aA[3]);
            TLB[q][0] = pkfrag(aB[0], aB[1]); TLB[q][1] = pkfrag(aB[2], aB[3]);
        };
        // q = 0 from prefetched rows
        leafstep(mkB0(pAa, pAb), mkB1(pAt), mkB0(pBa, pBb), mkB1(pBt), 0);
        #pragma unroll
        for (int q = 1; q < 4; q++) {
            const float* xrA = xbA + (size_t)(255 + 64*c + 4*rho + q) * 35;
            const float* xrB = xbB + (size_t)(255 + 64*c + 4*rho + q) * 35;
            leafstep(xB0(xrA, lq), xB1(xrA, lq), xB0(xrB, lq), xB1(xrB, lq), q);
        }
    }

    // ================= l7 (both trees; x-pass then TL-pass) =================
    s8v A7[4], B7[4];   // [E0,E1,O0,O1]
    {
        f4v aAE[4], aAO[4], aBE[4], aBO[4];
        #pragma unroll
        for (int i = 0; i < 4; i++) {
            f4v b = bias4(b1p + 32*(i>>1) + 8*lq + 4*(i&1));
            aAE[i] = b; aAO[i] = b; aBE[i] = b; aBO[i] = b;
        }
        {   // pass 1: x-part
            const float* xrAE = xbA + (size_t)(127 + 32*c + 2*rho) * 35;
            const float* xrBE = xbB + (size_t)(127 + 32*c + 2*rho) * 35;
            s8v xAE0 = xB0(xrAE, lq),      xAE1 = xB1(xrAE, lq);
            s8v xAO0 = xB0(xrAE + 35, lq), xAO1 = xB1(xrAE + 35, lq);
            s8v xBE0 = xB0(xrBE, lq),      xBE1 = xB1(xrBE, lq);
            s8v xBO0 = xB0(xrBE + 35, lq), xBO1 = xB1(xrBE + 35, lq);
            #pragma unroll
            for (int i = 0; i < 4; i++) {
                int sg = sigp(rho, i >> 1, i & 1);
                s8v w0 = wread(wt1s, 200, sg, 0, lq);
                s8v w1 = wread(wt1s, 200, sg, 1, lq);
                aAE[i] = mfma16(w0, xAE0, aAE[i]); aAE[i] = mfma16(w1, xAE1, aAE[i]);
                aAO[i] = mfma16(w0, xAO0, aAO[i]); aAO[i] = mfma16(w1, xAO1, aAO[i]);
                aBE[i] = mfma16(w0, xBE0, aBE[i]); aBE[i] = mfma16(w1, xBE1, aBE[i]);
                aBO[i] = mfma16(w0, xBO0, aBO[i]); aBO[i] = mfma16(w1, xBO1, aBO[i]);
            }
        }
        // pass 2: TL-part (each w read feeds 4 MFMAs)
        #pragma unroll
        for (int i = 0; i < 4; i++) {
            int sg = sigp(rho, i >> 1, i & 1);
            s8v w2 = wread(wt1s, 200, sg, 2, lq);
            s8v w3 = wread(wt1s, 200, sg, 3, lq);
            s8v w4 = wread(wt1s, 200, sg, 4, lq);
            s8v w5 = wread(wt1s, 200, sg, 5, lq);
            aAE[i] = mfma16(w2, TLA[0][0], aAE[i]); aAE[i] = mfma16(w3, TLA[0][1], aAE[i]);
            aAE[i] = mfma16(w4, TLA[1][0], aAE[i]); aAE[i] = mfma16(w5, TLA[1][1], aAE[i]);
            aAO[i] = mfma16(w2, TLA[2][0], aAO[i]); aAO[i] = mfma16(w3, TLA[2][1], aAO[i]);
            aAO[i] = mfma16(w4, TLA[3][0], aAO[i]); aAO[i] = mfma16(w5, TLA[3][1], aAO[i]);
            aBE[i] = mfma16(w2, TLB[0][0], aBE[i]); aBE[i] = mfma16(w3, TLB[0][1], aBE[i]);
            aBE[i] = mfma16(w4, TLB[1][0], aBE[i]); aBE[i] = mfma16(w5, TLB[1][1], aBE[i]);
            aBO[i] = mfma16(w2, TLB[2][0], aBO[i]); aBO[i] = mfma16(w3, TLB[2][1], aBO[i]);
            aBO[i] = mfma16(w4, TLB[3][0], aBO[i]); aBO[i] = mfma16(w5, TLB[3][1], aBO[i]);
        }
        A7[0] = pkfrag(aAE[0], aAE[1]); A7[1] = pkfrag(aAE[2], aAE[3]);
        A7[2] = pkfrag(aAO[0], aAO[1]); A7[3] = pkfrag(aAO[2], aAO[3]);
        B7[0] = pkfrag(aBE[0], aBE[1]); B7[1] = pkfrag(aBE[2], aBE[3]);
        B7[2] = pkfrag(aBO[0], aBO[1]); B7[3] = pkfrag(aBO[2], aBO[3]);
    }

    // ================= l6 (both trees) -> buf6 slices =================
    {
        const float* xrA6 = xbA + (size_t)(63 + 16*c + rho) * 35;
        const float* xrB6 = xbB + (size_t)(63 + 16*c + rho) * 35;
        s8v xA0 = xB0(xrA6, lq), xA1 = xB1(xrA6, lq);
        s8v xBv0 = xB0(xrB6, lq), xBv1 = xB1(xrB6, lq);
        u16* slA = buf6 + (2*pair) * 4096;
        u16* slB = slA + 4096;
        int r6 = 16*c + rho;
        int sw6 = SWZ(r6);
        #pragma unroll
        for (int cc = 0; cc < 4; cc++) {
            int sg = 16*cc + rho;
            s8v w0 = wread(wt1s, 200, sg, 0, lq);
            s8v w1 = wread(wt1s, 200, sg, 1, lq);
            s8v w2 = wread(wt1s, 200, sg, 2, lq);
            s8v w3 = wread(wt1s, 200, sg, 3, lq);
            s8v w4 = wread(wt1s, 200, sg, 4, lq);
            s8v w5 = wread(wt1s, 200, sg, 5, lq);
            f4v bb = bias4(b1p + 16*cc + 4*lq);
            f4v aA = bb, aB = bb;
            aA = mfma16(w0, xA0, aA);  aA = mfma16(w1, xA1, aA);
            aA = mfma16(w2, A7[0], aA); aA = mfma16(w3, A7[1], aA);
            aA = mfma16(w4, A7[2], aA); aA = mfma16(w5, A7[3], aA);
            aB = mfma16(w0, xBv0, aB); aB = mfma16(w1, xBv1, aB);
            aB = mfma16(w2, B7[0], aB); aB = mfma16(w3, B7[1], aB);
            aB = mfma16(w4, B7[2], aB); aB = mfma16(w5, B7[3], aB);
            int col = (16*cc + 4*lq) ^ sw6;
            uint2 dA; dA.x = pk2(aA[0], aA[1]); dA.y = pk2(aA[2], aA[3]);
            uint2 dB; dB.x = pk2(aB[0], aB[1]); dB.y = pk2(aB[2], aB[3]);
            *(uint2*)(slA + (size_t)r6 * 64 + col) = dA;
            *(uint2*)(slB + (size_t)r6 * 64 + col) = dB;
        }
    }
    __syncthreads();

    // ================= tail part 1: l5 half-tiles on ALL 8 waves =================
    const int  tt   = w & 3;                 // tree within block
    const int  half = (w >= 4) ? 1 : 0;      // 0 = E tile, 1 = O tile
    {
        const int tree = blockIdx.x * 4 + tt;
        u16* slice = buf6 + tt * 4096;
        const u16* xts_t = xts + tt * 1280;
        const float* xb = x0 + (size_t)tree * 511 * 35;

        s8v ch5[2][2];   // [pr][s]
        #pragma unroll
        for (int pr = 0; pr < 2; pr++) {
            int row = 4*rho + 2*half + pr;
            int sw = SWZ(row);
            ch5[pr][0] = *(const s8v*)(slice + (size_t)row*64 + ((     8*lq) ^ sw));
            ch5[pr][1] = *(const s8v*)(slice + (size_t)row*64 + ((32 + 8*lq) ^ sw));
        }
        const float* xr5 = xb + (size_t)(31 + 2*rho + half) * 35;
        s8v x50 = xB0(xr5, lq), x51 = xB1(xr5, lq);
        f4v a5[4];
        #pragma unroll
        for (int i = 0; i < 4; i++) a5[i] = bias4(b1p + 32*(i>>1) + 8*lq + 4*(i&1));
        #pragma unroll
        for (int i = 0; i < 4; i++) {
            int sg = sigp(rho, i >> 1, i & 1);
            s8v w0 = wread(wt1s, 200, sg, 0, lq);
            s8v w1 = wread(wt1s, 200, sg, 1, lq);
            s8v w2 = wread(wt1s, 200, sg, 2, lq);
            s8v w3 = wread(wt1s, 200, sg, 3, lq);
            s8v w4 = wread(wt1s, 200, sg, 4, lq);
            s8v w5 = wread(wt1s, 200, sg, 5, lq);
            a5[i] = mfma16(w0, x50, a5[i]);      a5[i] = mfma16(w1, x51, a5[i]);
            a5[i] = mfma16(w2, ch5[0][0], a5[i]); a5[i] = mfma16(w3, ch5[0][1], a5[i]);
            a5[i] = mfma16(w4, ch5[1][0], a5[i]); a5[i] = mfma16(w5, ch5[1][1], a5[i]);
        }
        s8v L5X0 = pkfrag(a5[0], a5[1]), L5X1 = pkfrag(a5[2], a5[3]);

        __syncthreads();   // all ch5 reads done block-wide
        if (half == 1) {   // O waves hand off their frags via slice rows 16..31
            *(s8v*)(slice + 1024 + (size_t)l * 8) = L5X0;
            *(s8v*)(slice + 1536 + (size_t)l * 8) = L5X1;
        }
        __syncthreads();   // handoff visible

        // ============== tail part 2: l4 + l3..l0 on waves 0..3 ==============
        if (half == 0) {
            s8v L5E0 = L5X0, L5E1 = L5X1;
            s8v L5O0 = *(const s8v*)(slice + 1024 + (size_t)l * 8);
            s8v L5O1 = *(const s8v*)(slice + 1536 + (size_t)l * 8);

            // ---- l4 -> h4 image in slice rows 0..15 (x from LDS image) ----
            {
                const u16* xr4 = xts_t + (15 + rho) * 40;
                s8v x40 = *(const s8v*)(xr4 + lq*8);
                s8v x41 = (s8v){0,0,0,0,0,0,0,0};
                if (lq == 0) x41 = *(const s8v*)(xr4 + 32);
                int sw4 = SWZ(rho);
                #pragma unroll
                for (int cc = 0; cc < 4; cc++) {
                    int sg = 16*cc + rho;
                    s8v w0 = wread(wt1s, 200, sg, 0, lq);
                    s8v w1 = wread(wt1s, 200, sg, 1, lq);
                    s8v w2 = wread(wt1s, 200, sg, 2, lq);
                    s8v w3 = wread(wt1s, 200, sg, 3, lq);
                    s8v w4 = wread(wt1s, 200, sg, 4, lq);
                    s8v w5 = wread(wt1s, 200, sg, 5, lq);
                    f4v a = bias4(b1p + 16*cc + 4*lq);
                    a = mfma16(w0, x40, a);  a = mfma16(w1, x41, a);
                    a = mfma16(w2, L5E0, a); a = mfma16(w3, L5E1, a);
                    a = mfma16(w4, L5O0, a); a = mfma16(w5, L5O1, a);
                    int col = (16*cc + 4*lq) ^ sw4;
                    uint2 d; d.x = pk2(a[0], a[1]); d.y = pk2(a[2], a[3]);
                    *(uint2*)(slice + (size_t)rho * 64 + col) = d;
                }
            }
            asm volatile("s_waitcnt lgkmcnt(0)" ::: "memory");

            // ---- l3..l0 (A=activations from LDS x image, B=weights) ----
            u16* tb0 = slice + 32 * 64;   // rows 32..63
            u16* tb1 = slice;             // rows 0..31 (h4 image dead after l3)
            float bv[4];
            #pragma unroll
            for (int ct = 0; ct < 4; ct++) bv[ct] = b1p[ct*16 + rho];
            f4v acc[4];

            auto tlevel = [&](int lo, const u16* cb) {
                const u16* xr = xts_t + (lo + rho) * 40;
                s8v a0 = *(const s8v*)(xr + lq*8);
                s8v a1 = (s8v){0,0,0,0,0,0,0,0};
                if (lq == 0) a1 = *(const s8v*)(xr + 32);
                #pragma unroll
                for (int ct = 0; ct < 4; ct++) acc[ct] = (f4v){bv[ct], bv[ct], bv[ct], bv[ct]};
                #pragma unroll
                for (int ct = 0; ct < 4; ct++) {
                    acc[ct] = mfma16(a0, wread(wt1s, 200, ct*16 + rho, 0, lq), acc[ct]);
                    acc[ct] = mfma16(a1, wread(wt1s, 200, ct*16 + rho, 1, lq), acc[ct]);
                }
                #pragma unroll
                for (int ks = 0; ks < 4; ks++) {
                    int k0 = ks*32 + lq*8;
                    int rr = 2*rho + (k0 >> 6);
                    s8v ach = *(const s8v*)(cb + (size_t)rr*64 + ((k0 & 63) ^ SWZ(rr)));
                    #pragma unroll
                    for (int ct = 0; ct < 4; ct++)
                        acc[ct] = mfma16(ach, wread(wt1s, 200, ct*16 + rho, 2 + ks, lq), acc[ct]);
                }
            };
            auto tstore = [&](u16* buf) {
                #pragma unroll
                for (int r = 0; r < 4; r++) {
                    int ro = lq*4 + r; int sw = SWZ(ro);
                    #pragma unroll
                    for (int ct = 0; ct < 4; ct++)
                        buf[ro*64 + ((ct*16 + rho) ^ sw)] = f2bf(fmaxf(acc[ct][r], 0.f));
                }
                asm volatile("s_waitcnt lgkmcnt(0)" ::: "memory");
            };

            tlevel(7, slice);  tstore(tb0);   // l3 (children = h4 image rows 0..15)
            tlevel(3, tb0);    tstore(tb1);   // l2
            tlevel(1, tb1);    tstore(tb0);   // l1
            tlevel(0, tb0);                   // l0
            if (lq == 0) {
                #pragma unroll
                for (int ct = 0; ct < 4; ct++)
                    h0out[(size_t)tree*64 + ct*16 + rho] = fmaxf(acc[ct][0], 0.f);
            }
        }
    }
}

// ---------------------------------------------------------------------------
__global__ void mean_kernel(const float* __restrict__ h0, float* __restrict__ mh)
{
    int idx = blockIdx.x * blockDim.x + threadIdx.x;   // 512*64
    if (idx < 512 * 64) {
        int g = idx >> 6, h = idx & 63;
        float s = 0.f;
        #pragma unroll
        for (int q = 0; q < 5; q++) s += h0[(size_t)(g * 5 + q) * 64 + h];
        mh[idx] = s * 0.2f;
    }
}

__global__ __launch_bounds__(64) void head_kernel(const float* __restrict__ x,
                                                  const float* __restrict__ mh,
                                                  const float* __restrict__ Wfc1,
                                                  const float* __restrict__ bfc1,
                                                  const float* __restrict__ Wfc2,
                                                  const float* __restrict__ bfc2,
                                                  float* __restrict__ out)
{
    __shared__ float sw[64];
    __shared__ float sh[64];
    int b = blockIdx.x, h = threadIdx.x;

    float a0 = 0.f, a1 = 0.f, a2 = 0.f, a3 = 0.f;
    const float* xr = x + (size_t)b * 512;
    for (int g = 0; g < 512; g += 4) {
        a0 = fmaf(xr[g + 0], mh[(g + 0) * 64 + h], a0);
        a1 = fmaf(xr[g + 1], mh[(g + 1) * 64 + h], a1);
        a2 = fmaf(xr[g + 2], mh[(g + 2) * 64 + h], a2);
        a3 = fmaf(xr[g + 3], mh[(g + 3) * 64 + h], a3);
    }
    sw[h] = (a0 + a1) + (a2 + a3);
    __syncthreads();

    float acc = bfc1[h];
    #pragma unroll 8
    for (int k = 0; k < 64; k++) acc = fmaf(Wfc1[h * 64 + k], sw[k], acc);
    sh[h] = fmaxf(acc, 0.f);
    __syncthreads();

    if (h < 8) {
        float o = bfc2[h];
        #pragma unroll 8
        for (int f = 0; f < 64; f++) o = fmaf(Wfc2[h * 64 + f], sh[f], o);
        out[(size_t)b * 8 + h] = o;
    }
}

// ---------------------------------------------------------------------------
extern "C" void kernel_launch(void* const* d_in, const int* in_sizes, int n_in,
                              void* d_out, int out_size, void* d_ws, size_t ws_size,
                              hipStream_t stream)
{
    (void)in_sizes; (void)n_in; (void)out_size; (void)ws_size;
    const float* x     = (const float*)d_in[0];
    const float* x0    = (const float*)d_in[1];
    const float* W_emb = (const float*)d_in[2];
    const float* b_emb = (const float*)d_in[3];
    const float* W0    = (const float*)d_in[4];
    const float* b0    = (const float*)d_in[5];
    const float* W1    = (const float*)d_in[6];
    const float* b1    = (const float*)d_in[7];
    const float* Wfc1  = (const float*)d_in[8];
    const float* bfc1  = (const float*)d_in[9];
    const float* Wfc2  = (const float*)d_in[10];
    const float* bfc2  = (const float*)d_in[11];
    float* out = (float*)d_out;

    u16* wt1   = (u16*)d_ws;                 // 64*192
    u16* wt0   = wt1 + 64 * 192;             // 64*64
    float* b1p = (float*)(wt0 + 64 * 64);
    float* b0p = b1p + 64;
    float* h0  = b0p + 64;                   // 2560*64 f32
    float* mh  = h0 + 2560 * 64;             // 512*64 f32

    prep_kernel<<<65, 256, 0, stream>>>(W_emb, b_emb, W0, b0, W1, b1, wt1, wt0, b1p, b0p);
    tree_all<<<640, 512, 0, stream>>>(x0, wt1, wt0, b1p, b0p, h0);
    mean_kernel<<<128, 256, 0, stream>>>(h0, mh);
    head_kernel<<<512, 64, 0, stream>>>(x, mh, Wfc1, bfc1, Wfc2, bfc2, out);
}

// Round 17
// 88.434 us; speedup vs baseline: 1.0734x; 1.0734x over previous
//
#include <hip/hip_runtime.h>
#include <hip/hip_bf16.h>

// ---------------------------------------------------------------------------
// Round 17 = exact revert to Round 11 (best measured: 88.7 us).
// Barrier-free per-wave subtree chains (sigma-permuted swapped MFMA keeps h
// lane-local leaf->l7->l6), 2 trees/wave, fused l5..l0 tail, block = 4 trees
// x 8 waves, grid 640. Session conclusion: structure plateau at ~89 us —
// no pipe >20%, residency levers (VGPR<=128, LDS<=80KB) both pinned;
// R12-R16 perturbations all null/negative.
// ---------------------------------------------------------------------------

typedef __attribute__((ext_vector_type(8))) short s8v;   // 8 bf16
typedef __attribute__((ext_vector_type(4))) float f4v;   // MFMA C/D
typedef unsigned short u16;
typedef unsigned int   u32;

__device__ __forceinline__ u16 f2bf(float f) {
    return __builtin_bit_cast(u16, __float2bfloat16(f));
}
__device__ __forceinline__ f4v mfma16(s8v a, s8v b, f4v c) {
    return __builtin_amdgcn_mfma_f32_16x16x32_bf16(a, b, c, 0, 0, 0);
}
#define SWZ(r) ((((r) & 1) | (((r) >> 1) & 6)) << 3)

__device__ __forceinline__ u32 pk2(float a, float b) {
    return (u32)f2bf(fmaxf(a, 0.f)) | ((u32)f2bf(fmaxf(b, 0.f)) << 16);
}
__device__ __forceinline__ s8v pkfrag(f4v h0, f4v h1) {
    int4 d;
    d.x = (int)pk2(h0[0], h0[1]); d.y = (int)pk2(h0[2], h0[3]);
    d.z = (int)pk2(h1[0], h1[1]); d.w = (int)pk2(h1[2], h1[3]);
    return __builtin_bit_cast(s8v, d);
}
__device__ __forceinline__ s8v xB0(const float* __restrict__ xr, int lq) {
    float4 A = *(const float4*)(xr + lq * 8);
    float4 B = *(const float4*)(xr + lq * 8 + 4);
    s8v r;
    r[0]=(short)f2bf(A.x); r[1]=(short)f2bf(A.y); r[2]=(short)f2bf(A.z); r[3]=(short)f2bf(A.w);
    r[4]=(short)f2bf(B.x); r[5]=(short)f2bf(B.y); r[6]=(short)f2bf(B.z); r[7]=(short)f2bf(B.w);
    return r;
}
__device__ __forceinline__ s8v xB1(const float* __restrict__ xr, int lq) {
    s8v r = (s8v){0,0,0,0,0,0,0,0};
    if (lq == 0) {
        float4 T = *(const float4*)(xr + 31);   // k31..34
        r[0]=(short)f2bf(T.y); r[1]=(short)f2bf(T.z); r[2]=(short)f2bf(T.w);
    }
    return r;
}
__device__ __forceinline__ s8v wread(const u16* w, int stride, int row, int ks, int lq) {
    return *(const s8v*)(w + row * stride + ks * 32 + lq * 8);
}
__device__ __forceinline__ f4v bias4(const float* __restrict__ b) {
    float4 t = *(const float4*)b; return (f4v){t.x, t.y, t.z, t.w};
}
__device__ __forceinline__ int sigp(int rho, int s, int h) {
    return 32*s + 4*h + ((rho & 12) << 1) + (rho & 3);
}

// ---------------------------------------------------------------------------
__global__ void prep_kernel(const float* __restrict__ W_emb, const float* __restrict__ b_emb,
                            const float* __restrict__ W0, const float* __restrict__ b0,
                            const float* __restrict__ W1, const float* __restrict__ b1,
                            u16* __restrict__ wt1, u16* __restrict__ wt0,
                            float* __restrict__ b1p, float* __restrict__ b0p)
{
    int idx = blockIdx.x * 256 + threadIdx.x;
    if (idx < 64 * 192) {
        int h = idx / 192, k = idx % 192;
        float v;
        if (k < 32) { v = 0.f; for (int e = 0; e < 64; e++) v = fmaf(W1[h*195+e], W_emb[e*32+k], v); }
        else if (k < 35)  v = W1[h*195 + 64 + (k - 32)];
        else if (k < 64)  v = 0.f;
        else              v = W1[h*195 + 67 + (k - 64)];   // hL(64) then hR(64)
        wt1[h*192 + k] = f2bf(v);
    } else if (idx < 64*192 + 64*64) {
        int j = idx - 64*192; int h = j >> 6, k = j & 63;
        float v;
        if (k < 32)      { v = 0.f; for (int e = 0; e < 64; e++) v = fmaf(W0[h*67+e], W_emb[e*32+k], v); }
        else if (k < 35)   v = W0[h*67 + 64 + (k - 32)];
        else               v = 0.f;
        wt0[h*64 + k] = f2bf(v);
    } else if (idx < 64*192 + 64*64 + 64) {
        int h = idx - (64*192 + 64*64);
        float v = b1[h];
        for (int e = 0; e < 64; e++) v = fmaf(W1[h*195+e], b_emb[e], v);
        b1p[h] = v;
    } else if (idx < 64*192 + 64*64 + 128) {
        int h = idx - (64*192 + 64*64 + 64);
        float v = b0[h];
        for (int e = 0; e < 64; e++) v = fmaf(W0[h*67+e], b_emb[e], v);
        b0p[h] = v;
    }
}

// ---------------------------------------------------------------------------
__global__ __launch_bounds__(512, 2) void tree_all(
    const float* __restrict__ x0,
    const u16* __restrict__ wt1g, const u16* __restrict__ wt0g,
    const float* __restrict__ b1p, const float* __restrict__ b0p,
    float* __restrict__ h0out)
{
    __shared__ __align__(16) u16 wt1s[64 * 200];        // 25.6 KB, pad stride 200
    __shared__ __align__(16) u16 wt0s[64 * 40 + 64];    // 5.25 KB + guard
    __shared__ __align__(16) u16 buf6[4 * 64 * 64];     // 32 KB: 4 tree-slices

    const int tid = threadIdx.x;
    const int l   = tid & 63;
    const int w   = tid >> 6;      // 0..7
    const int lq  = l >> 4;
    const int rho = l & 15;
    const int pair = w >> 2;       // tree-pair within block
    const int c    = w & 3;        // chain
    const int tA = blockIdx.x * 4 + 2 * pair;
    const int tB = tA + 1;
    const float* xbA = x0 + (size_t)tA * 511 * 35;
    const float* xbB = x0 + (size_t)tB * 511 * 35;

    // ---- stage weights (coalesced dwords) ----
    {
        u32* d1 = (u32*)wt1s; const u32* s1 = (const u32*)wt1g;
        #pragma unroll
        for (int t = 0; t < 12; t++) {
            int i = t*512 + tid;                 // 6144 dwords exactly
            int row = i / 96, kk = i - row*96;
            d1[row*100 + kk] = s1[row*96 + kk];
        }
        u32* d0 = (u32*)wt0s; const u32* s0 = (const u32*)wt0g;
        #pragma unroll
        for (int t = 0; t < 3; t++) {
            int i = t*512 + tid;
            if (i < 1280) { int row = i / 20, kk = i - row*20; d0[row*20 + kk] = s0[row*32 + kk]; }
        }
        if (tid < 32) ((u32*)(wt0s + 64*40))[tid] = 0;   // guard
    }
    __syncthreads();

    // ================= leaf (both trees share WL) =================
    s8v TLA[4][2], TLB[4][2];
    {
        s8v WL[4][2]; f4v bL[4];
        #pragma unroll
        for (int i = 0; i < 4; i++) {
            int sg = sigp(rho, i >> 1, i & 1);
            WL[i][0] = wread(wt0s, 40, sg, 0, lq);
            WL[i][1] = wread(wt0s, 40, sg, 1, lq);
            bL[i] = bias4(b0p + 32*(i>>1) + 8*lq + 4*(i&1));
        }
        #pragma unroll
        for (int q = 0; q < 4; q++) {
            const float* xrA = xbA + (size_t)(255 + 64*c + 4*rho + q) * 35;
            const float* xrB = xbB + (size_t)(255 + 64*c + 4*rho + q) * 35;
            s8v xaA = xB0(xrA, lq), xtA = xB1(xrA, lq);
            s8v xaB = xB0(xrB, lq), xtB = xB1(xrB, lq);
            f4v aA[4], aB[4];
            #pragma unroll
            for (int i = 0; i < 4; i++) { aA[i] = bL[i]; aB[i] = bL[i]; }
            #pragma unroll
            for (int i = 0; i < 4; i++) {
                aA[i] = mfma16(WL[i][0], xaA, aA[i]);
                aA[i] = mfma16(WL[i][1], xtA, aA[i]);
                aB[i] = mfma16(WL[i][0], xaB, aB[i]);
                aB[i] = mfma16(WL[i][1], xtB, aB[i]);
            }
            TLA[q][0] = pkfrag(aA[0], aA[1]); TLA[q][1] = pkfrag(aA[2], aA[3]);
            TLB[q][0] = pkfrag(aB[0], aB[1]); TLB[q][1] = pkfrag(aB[2], aB[3]);
        }
    }

    // ================= l7 (both trees; x-pass then TL-pass) =================
    s8v A7[4], B7[4];   // [E0,E1,O0,O1]
    {
        f4v aAE[4], aAO[4], aBE[4], aBO[4];
        #pragma unroll
        for (int i = 0; i < 4; i++) {
            f4v b = bias4(b1p + 32*(i>>1) + 8*lq + 4*(i&1));
            aAE[i] = b; aAO[i] = b; aBE[i] = b; aBO[i] = b;
        }
        {   // pass 1: x-part
            const float* xrAE = xbA + (size_t)(127 + 32*c + 2*rho) * 35;
            const float* xrBE = xbB + (size_t)(127 + 32*c + 2*rho) * 35;
            s8v xAE0 = xB0(xrAE, lq),      xAE1 = xB1(xrAE, lq);
            s8v xAO0 = xB0(xrAE + 35, lq), xAO1 = xB1(xrAE + 35, lq);
            s8v xBE0 = xB0(xrBE, lq),      xBE1 = xB1(xrBE, lq);
            s8v xBO0 = xB0(xrBE + 35, lq), xBO1 = xB1(xrBE + 35, lq);
            #pragma unroll
            for (int i = 0; i < 4; i++) {
                int sg = sigp(rho, i >> 1, i & 1);
                s8v w0 = wread(wt1s, 200, sg, 0, lq);
                s8v w1 = wread(wt1s, 200, sg, 1, lq);
                aAE[i] = mfma16(w0, xAE0, aAE[i]); aAE[i] = mfma16(w1, xAE1, aAE[i]);
                aAO[i] = mfma16(w0, xAO0, aAO[i]); aAO[i] = mfma16(w1, xAO1, aAO[i]);
                aBE[i] = mfma16(w0, xBE0, aBE[i]); aBE[i] = mfma16(w1, xBE1, aBE[i]);
                aBO[i] = mfma16(w0, xBO0, aBO[i]); aBO[i] = mfma16(w1, xBO1, aBO[i]);
            }
        }
        // pass 2: TL-part (each w read feeds 4 MFMAs)
        #pragma unroll
        for (int i = 0; i < 4; i++) {
            int sg = sigp(rho, i >> 1, i & 1);
            s8v w2 = wread(wt1s, 200, sg, 2, lq);
            s8v w3 = wread(wt1s, 200, sg, 3, lq);
            s8v w4 = wread(wt1s, 200, sg, 4, lq);
            s8v w5 = wread(wt1s, 200, sg, 5, lq);
            aAE[i] = mfma16(w2, TLA[0][0], aAE[i]); aAE[i] = mfma16(w3, TLA[0][1], aAE[i]);
            aAE[i] = mfma16(w4, TLA[1][0], aAE[i]); aAE[i] = mfma16(w5, TLA[1][1], aAE[i]);
            aAO[i] = mfma16(w2, TLA[2][0], aAO[i]); aAO[i] = mfma16(w3, TLA[2][1], aAO[i]);
            aAO[i] = mfma16(w4, TLA[3][0], aAO[i]); aAO[i] = mfma16(w5, TLA[3][1], aAO[i]);
            aBE[i] = mfma16(w2, TLB[0][0], aBE[i]); aBE[i] = mfma16(w3, TLB[0][1], aBE[i]);
            aBE[i] = mfma16(w4, TLB[1][0], aBE[i]); aBE[i] = mfma16(w5, TLB[1][1], aBE[i]);
            aBO[i] = mfma16(w2, TLB[2][0], aBO[i]); aBO[i] = mfma16(w3, TLB[2][1], aBO[i]);
            aBO[i] = mfma16(w4, TLB[3][0], aBO[i]); aBO[i] = mfma16(w5, TLB[3][1], aBO[i]);
        }
        A7[0] = pkfrag(aAE[0], aAE[1]); A7[1] = pkfrag(aAE[2], aAE[3]);
        A7[2] = pkfrag(aAO[0], aAO[1]); A7[3] = pkfrag(aAO[2], aAO[3]);
        B7[0] = pkfrag(aBE[0], aBE[1]); B7[1] = pkfrag(aBE[2], aBE[3]);
        B7[2] = pkfrag(aBO[0], aBO[1]); B7[3] = pkfrag(aBO[2], aBO[3]);
    }

    // ================= l6 (both trees) -> buf6 slices =================
    {
        const float* xrA6 = xbA + (size_t)(63 + 16*c + rho) * 35;
        const float* xrB6 = xbB + (size_t)(63 + 16*c + rho) * 35;
        s8v xA0 = xB0(xrA6, lq), xA1 = xB1(xrA6, lq);
        s8v xBv0 = xB0(xrB6, lq), xBv1 = xB1(xrB6, lq);
        u16* slA = buf6 + (2*pair) * 4096;
        u16* slB = slA + 4096;
        int r6 = 16*c + rho;
        int sw6 = SWZ(r6);
        #pragma unroll
        for (int cc = 0; cc < 4; cc++) {
            int sg = 16*cc + rho;
            s8v w0 = wread(wt1s, 200, sg, 0, lq);
            s8v w1 = wread(wt1s, 200, sg, 1, lq);
            s8v w2 = wread(wt1s, 200, sg, 2, lq);
            s8v w3 = wread(wt1s, 200, sg, 3, lq);
            s8v w4 = wread(wt1s, 200, sg, 4, lq);
            s8v w5 = wread(wt1s, 200, sg, 5, lq);
            f4v bb = bias4(b1p + 16*cc + 4*lq);
            f4v aA = bb, aB = bb;
            aA = mfma16(w0, xA0, aA);  aA = mfma16(w1, xA1, aA);
            aA = mfma16(w2, A7[0], aA); aA = mfma16(w3, A7[1], aA);
            aA = mfma16(w4, A7[2], aA); aA = mfma16(w5, A7[3], aA);
            aB = mfma16(w0, xBv0, aB); aB = mfma16(w1, xBv1, aB);
            aB = mfma16(w2, B7[0], aB); aB = mfma16(w3, B7[1], aB);
            aB = mfma16(w4, B7[2], aB); aB = mfma16(w5, B7[3], aB);
            int col = (16*cc + 4*lq) ^ sw6;
            uint2 dA; dA.x = pk2(aA[0], aA[1]); dA.y = pk2(aA[2], aA[3]);
            uint2 dB; dB.x = pk2(aB[0], aB[1]); dB.y = pk2(aB[2], aB[3]);
            *(uint2*)(slA + (size_t)r6 * 64 + col) = dA;
            *(uint2*)(slB + (size_t)r6 * 64 + col) = dB;
        }
    }
    __syncthreads();

    // ================= tail: waves 0..3, one tree each =================
    if (w < 4) {
        const int tree = blockIdx.x * 4 + w;
        u16* slice = buf6 + w * 4096;
        const float* xb = x0 + (size_t)tree * 511 * 35;

        // ---- l5 ----
        s8v ch5[2][2][2];
        #pragma unroll
        for (int d5 = 0; d5 < 2; d5++)
        #pragma unroll
        for (int pr = 0; pr < 2; pr++) {
            int row = 4*rho + 2*d5 + pr;
            int sw = SWZ(row);
            ch5[d5][pr][0] = *(const s8v*)(slice + (size_t)row*64 + ((     8*lq) ^ sw));
            ch5[d5][pr][1] = *(const s8v*)(slice + (size_t)row*64 + ((32 + 8*lq) ^ sw));
        }
        const float* xr5E = xb + (size_t)(31 + 2*rho) * 35;
        s8v x5E0 = xB0(xr5E, lq),      x5E1 = xB1(xr5E, lq);
        s8v x5O0 = xB0(xr5E + 35, lq), x5O1 = xB1(xr5E + 35, lq);
        f4v aE[4], aO[4];
        #pragma unroll
        for (int i = 0; i < 4; i++) {
            f4v b = bias4(b1p + 32*(i>>1) + 8*lq + 4*(i&1));
            aE[i] = b; aO[i] = b;
        }
        #pragma unroll
        for (int i = 0; i < 4; i++) {
            int sg = sigp(rho, i >> 1, i & 1);
            s8v w0 = wread(wt1s, 200, sg, 0, lq);
            s8v w1 = wread(wt1s, 200, sg, 1, lq);
            s8v w2 = wread(wt1s, 200, sg, 2, lq);
            s8v w3 = wread(wt1s, 200, sg, 3, lq);
            s8v w4 = wread(wt1s, 200, sg, 4, lq);
            s8v w5 = wread(wt1s, 200, sg, 5, lq);
            aE[i] = mfma16(w0, x5E0, aE[i]); aE[i] = mfma16(w1, x5E1, aE[i]);
            aE[i] = mfma16(w2, ch5[0][0][0], aE[i]); aE[i] = mfma16(w3, ch5[0][0][1], aE[i]);
            aE[i] = mfma16(w4, ch5[0][1][0], aE[i]); aE[i] = mfma16(w5, ch5[0][1][1], aE[i]);
            aO[i] = mfma16(w0, x5O0, aO[i]); aO[i] = mfma16(w1, x5O1, aO[i]);
            aO[i] = mfma16(w2, ch5[1][0][0], aO[i]); aO[i] = mfma16(w3, ch5[1][0][1], aO[i]);
            aO[i] = mfma16(w4, ch5[1][1][0], aO[i]); aO[i] = mfma16(w5, ch5[1][1][1], aO[i]);
        }
        s8v L5E0 = pkfrag(aE[0], aE[1]), L5E1 = pkfrag(aE[2], aE[3]);
        s8v L5O0 = pkfrag(aO[0], aO[1]), L5O1 = pkfrag(aO[2], aO[3]);

        // ---- l4 -> h4 image in slice rows 0..15 (SWZ'd) ----
        {
            const float* xr4 = xb + (size_t)(15 + rho) * 35;
            s8v x40 = xB0(xr4, lq), x41 = xB1(xr4, lq);
            int sw4 = SWZ(rho);
            #pragma unroll
            for (int cc = 0; cc < 4; cc++) {
                int sg = 16*cc + rho;
                s8v w0 = wread(wt1s, 200, sg, 0, lq);
                s8v w1 = wread(wt1s, 200, sg, 1, lq);
                s8v w2 = wread(wt1s, 200, sg, 2, lq);
                s8v w3 = wread(wt1s, 200, sg, 3, lq);
                s8v w4 = wread(wt1s, 200, sg, 4, lq);
                s8v w5 = wread(wt1s, 200, sg, 5, lq);
                f4v a = bias4(b1p + 16*cc + 4*lq);
                a = mfma16(w0, x40, a);  a = mfma16(w1, x41, a);
                a = mfma16(w2, L5E0, a); a = mfma16(w3, L5E1, a);
                a = mfma16(w4, L5O0, a); a = mfma16(w5, L5O1, a);
                int col = (16*cc + 4*lq) ^ sw4;
                uint2 d; d.x = pk2(a[0], a[1]); d.y = pk2(a[2], a[3]);
                *(uint2*)(slice + (size_t)rho * 64 + col) = d;
            }
        }
        asm volatile("s_waitcnt lgkmcnt(0)" ::: "memory");

        // ---- l3..l0 (A=activations, B=weights from wt1s) ----
        u16* tb0 = slice + 32 * 64;   // rows 32..63
        u16* tb1 = slice;             // rows 0..31 (h4 image dead after l3)
        float bv[4];
        #pragma unroll
        for (int ct = 0; ct < 4; ct++) bv[ct] = b1p[ct*16 + rho];
        f4v acc[4];

        auto tlevel = [&](int lo, const u16* cb) {
            const float* xr = xb + (size_t)(lo + rho) * 35;
            s8v a0 = xB0(xr, lq), a1 = xB1(xr, lq);
            #pragma unroll
            for (int ct = 0; ct < 4; ct++) acc[ct] = (f4v){bv[ct], bv[ct], bv[ct], bv[ct]};
            #pragma unroll
            for (int ct = 0; ct < 4; ct++) {
                acc[ct] = mfma16(a0, wread(wt1s, 200, ct*16 + rho, 0, lq), acc[ct]);
                acc[ct] = mfma16(a1, wread(wt1s, 200, ct*16 + rho, 1, lq), acc[ct]);
            }
            #pragma unroll
            for (int ks = 0; ks < 4; ks++) {
                int k0 = ks*32 + lq*8;
                int rr = 2*rho + (k0 >> 6);
                s8v ach = *(const s8v*)(cb + (size_t)rr*64 + ((k0 & 63) ^ SWZ(rr)));
                #pragma unroll
                for (int ct = 0; ct < 4; ct++)
                    acc[ct] = mfma16(ach, wread(wt1s, 200, ct*16 + rho, 2 + ks, lq), acc[ct]);
            }
        };
        auto tstore = [&](u16* buf) {
            #pragma unroll
            for (int r = 0; r < 4; r++) {
                int ro = lq*4 + r; int sw = SWZ(ro);
                #pragma unroll
                for (int ct = 0; ct < 4; ct++)
                    buf[ro*64 + ((ct*16 + rho) ^ sw)] = f2bf(fmaxf(acc[ct][r], 0.f));
            }
            asm volatile("s_waitcnt lgkmcnt(0)" ::: "memory");
        };

        tlevel(7, slice);  tstore(tb0);   // l3 (children = h4 image rows 0..15)
        tlevel(3, tb0);    tstore(tb1);   // l2
        tlevel(1, tb1);    tstore(tb0);   // l1
        tlevel(0, tb0);                   // l0
        if (lq == 0) {
            #pragma unroll
            for (int ct = 0; ct < 4; ct++)
                h0out[(size_t)tree*64 + ct*16 + rho] = fmaxf(acc[ct][0], 0.f);
        }
    }
}

// ---------------------------------------------------------------------------
__global__ void mean_kernel(const float* __restrict__ h0, float* __restrict__ mh)
{
    int idx = blockIdx.x * blockDim.x + threadIdx.x;   // 512*64
    if (idx < 512 * 64) {
        int g = idx >> 6, h = idx & 63;
        float s = 0.f;
        #pragma unroll
        for (int q = 0; q < 5; q++) s += h0[(size_t)(g * 5 + q) * 64 + h];
        mh[idx] = s * 0.2f;
    }
}

__global__ __launch_bounds__(64) void head_kernel(const float* __restrict__ x,
                                                  const float* __restrict__ mh,
                                                  const float* __restrict__ Wfc1,
                                                  const float* __restrict__ bfc1,
                                                  const float* __restrict__ Wfc2,
                                                  const float* __restrict__ bfc2,
                                                  float* __restrict__ out)
{
    __shared__ float sw[64];
    __shared__ float sh[64];
    int b = blockIdx.x, h = threadIdx.x;

    float a0 = 0.f, a1 = 0.f, a2 = 0.f, a3 = 0.f;
    const float* xr = x + (size_t)b * 512;
    for (int g = 0; g < 512; g += 4) {
        a0 = fmaf(xr[g + 0], mh[(g + 0) * 64 + h], a0);
        a1 = fmaf(xr[g + 1], mh[(g + 1) * 64 + h], a1);
        a2 = fmaf(xr[g + 2], mh[(g + 2) * 64 + h], a2);
        a3 = fmaf(xr[g + 3], mh[(g + 3) * 64 + h], a3);
    }
    sw[h] = (a0 + a1) + (a2 + a3);
    __syncthreads();

    float acc = bfc1[h];
    #pragma unroll 8
    for (int k = 0; k < 64; k++) acc = fmaf(Wfc1[h * 64 + k], sw[k], acc);
    sh[h] = fmaxf(acc, 0.f);
    __syncthreads();

    if (h < 8) {
        float o = bfc2[h];
        #pragma unroll 8
        for (int f = 0; f < 64; f++) o = fmaf(Wfc2[h * 64 + f], sh[f], o);
        out[(size_t)b * 8 + h] = o;
    }
}

// ---------------------------------------------------------------------------
extern "C" void kernel_launch(void* const* d_in, const int* in_sizes, int n_in,
                              void* d_out, int out_size, void* d_ws, size_t ws_size,
                              hipStream_t stream)
{
    (void)in_sizes; (void)n_in; (void)out_size; (void)ws_size;
    const float* x     = (const float*)d_in[0];
    const float* x0    = (const float*)d_in[1];
    const float* W_emb = (const float*)d_in[2];
    const float* b_emb = (const float*)d_in[3];
    const float* W0    = (const float*)d_in[4];
    const float* b0    = (const float*)d_in[5];
    const float* W1    = (const float*)d_in[6];
    const float* b1    = (const float*)d_in[7];
    const float* Wfc1  = (const float*)d_in[8];
    const float* bfc1  = (const float*)d_in[9];
    const float* Wfc2  = (const float*)d_in[10];
    const float* bfc2  = (const float*)d_in[11];
    float* out = (float*)d_out;

    u16* wt1   = (u16*)d_ws;                 // 64*192
    u16* wt0   = wt1 + 64 * 192;             // 64*64
    float* b1p = (float*)(wt0 + 64 * 64);
    float* b0p = b1p + 64;
    float* h0  = b0p + 64;                   // 2560*64 f32
    float* mh  = h0 + 2560 * 64;             // 512*64 f32

    prep_kernel<<<65, 256, 0, stream>>>(W_emb, b_emb, W0, b0, W1, b1, wt1, wt0, b1p, b0p);
    tree_all<<<640, 512, 0, stream>>>(x0, wt1, wt0, b1p, b0p, h0);
    mean_kernel<<<128, 256, 0, stream>>>(h0, mh);
    head_kernel<<<512, 64, 0, stream>>>(x, mh, Wfc1, bfc1, Wfc2, bfc2, out);
}